// Round 3
// baseline (184.226 us; speedup 1.0000x reference)
//
#include <hip/hip_runtime.h>
#include <math.h>

#define NROWS 65536      // B*T
#define DIM   64
#define KCODE 1024
#define TAU_M 3e-2f      // packed-margin threshold (covers bf16-split + mantissa-trunc err)

typedef __attribute__((ext_vector_type(8))) short short8;
typedef __bf16 bf16_t;
typedef bf16_t bf16x8 __attribute__((ext_vector_type(8)));
typedef __attribute__((ext_vector_type(4))) float f32x4;

union B8 { bf16x8 v; short8 s; ushort u[8]; };

// ws layout (bytes):
//   [0      .. 262143]  ushort emb_frag  (1024 codes x 64 dims x {hi,lo}) in MFMA B order
//   [262144 .. 266239]  float  e2h[1024]  = -||e||^2 / 2
//   [266240 .. 270335]  int    counts[1024]
//   [270336 .. 270339]  float  sse
//   [270352 .. 335887]  uchar  flags[NROWS]
#define WS_EMBF(ws)   ((ushort*)(ws))
#define WS_E2H(ws)    ((float*)((char*)(ws) + 262144))
#define WS_COUNTS(ws) ((int*)((char*)(ws) + 266240))
#define WS_SSE(ws)    ((float*)((char*)(ws) + 270336))
#define WS_FLAGS(ws)  ((unsigned char*)(ws) + 270352)

__device__ __forceinline__ ushort f2bf(float x) {
  unsigned u = __float_as_uint(x);
  u += 0x7FFFu + ((u >> 16) & 1u);           // RNE
  return (ushort)(u >> 16);
}
__device__ __forceinline__ float bf2f(ushort h) {
  return __uint_as_float(((unsigned)h) << 16);
}

__device__ __forceinline__ void gload16(const int4* g, int4* l) {
  __builtin_amdgcn_global_load_lds((const __attribute__((address_space(1))) void*)g,
                                   (__attribute__((address_space(3))) void*)l, 16, 0, 0);
}

// ---------------------------------------------------------------- init ----
// grid 16 blocks x 256 threads; block = one 64-code strip. Builds the 16KB
// fragment image in LDS, writes it out coalesced; also e2h, counts, sse.
__global__ __launch_bounds__(256) void vq_init(const float* __restrict__ emb, void* ws) {
  __shared__ __align__(16) ushort simg[8192];   // 16KB strip image
  __shared__ float e2p[256];

  const int s = blockIdx.x, t = threadIdx.x;
  const int c  = t >> 2;                 // local code 0..63
  const int gc = s * 64 + c;             // global code
  const int d0 = (t & 3) * 16;           // dim range start
  const float4* ep = (const float4*)(emb + (size_t)gc * DIM + d0);

  const int tile = (c >> 4) & 3, colv = c & 15;
  float acc = 0.f;
#pragma unroll
  for (int j = 0; j < 4; ++j) {
    float4 v = ep[j];
    float xs[4] = {v.x, v.y, v.z, v.w};
#pragma unroll
    for (int u = 0; u < 4; ++u) {
      int d = d0 + j * 4 + u;
      float x = xs[u];
      ushort hs = f2bf(x);
      ushort ls = f2bf(x - bf2f(hs));
      int ks = d >> 5, kq = (d >> 3) & 3, e = d & 7;
      int lane = colv + kq * 16;
      int off = tile * 2048 + ks * 1024 + lane * 8 + e;
      simg[off] = hs;
      simg[off + 512] = ls;
      acc += x * x;
    }
  }
  e2p[t] = acc;
  __syncthreads();
  if (t < 64) {
    float ssum = (e2p[t * 4] + e2p[t * 4 + 1]) + (e2p[t * 4 + 2] + e2p[t * 4 + 3]);
    WS_E2H(ws)[s * 64 + t] = -0.5f * ssum;
    WS_COUNTS(ws)[s * 64 + t] = 0;
  }
  if (s == 0 && t == 0) *WS_SSE(ws) = 0.f;
  const int4* si = (const int4*)simg;
  int4* dst = (int4*)WS_EMBF(ws) + (size_t)s * 1024;
#pragma unroll
  for (int j = 0; j < 4; ++j) dst[j * 256 + t] = si[j * 256 + t];
}

// ---------------------------------------------------------------- main ----
// 1024 threads = 16 waves = 4 row-groups x 4 code-groups; block = 256 rows;
// grid = 256 (1 block/CU, 4 waves/SIMD). Code-group owns 4 strips (256 codes),
// double-buffered via global_load_lds.
__global__ __launch_bounds__(1024) void vq_main(const float* __restrict__ z,
                                                const float* __restrict__ emb,
                                                void* ws,
                                                float* __restrict__ outp) {
  __shared__ __align__(16) int4 ebuf[4][2][1024];   // [cgroup][dbuf][16KB strip]
  __shared__ float e2s[KCODE];
  __shared__ int   win[256];
  __shared__ float ssew[16];

  const int tid  = threadIdx.x;
  const int lane = tid & 63, w = tid >> 6;
  const int rg = w & 3, cg = w >> 2;
  const int col = lane & 15, kq = lane >> 4;
  const int ct = tid & 255;                        // index within code-group
  const int rowbase = blockIdx.x * 256 + rg * 64;
  const int invLane = 1023 - col;

  const int4* ef4 = (const int4*)WS_EMBF(ws);

  // prologue stage: strip 0 of this cgroup -> ebuf[cg][0] (async DMA)
  {
    const int4* src = ef4 + (size_t)(cg * 4) * 1024 + ct;
    int4* dst = &ebuf[cg][0][ct];
#pragma unroll
    for (int k = 0; k < 4; ++k) gload16(src + k * 256, dst + k * 256);
  }
  // stage e2h -> LDS (4KB)
  if (tid < 256) ((float4*)e2s)[tid] = ((const float4*)WS_E2H(ws))[tid];

  // A fragments: 4 row-groups-of-16 x 2 ksteps, hi+lo, in registers all kernel
  B8 ah[4][2], al[4][2];
#pragma unroll
  for (int g = 0; g < 4; ++g) {
    int row = rowbase + g * 16 + col;
    const float* zr = z + (size_t)row * DIM;
#pragma unroll
    for (int ks = 0; ks < 2; ++ks) {
      const float4* p = (const float4*)(zr + ks * 32 + kq * 8);
      float4 x0 = p[0], x1 = p[1];
      float vv[8] = {x0.x, x0.y, x0.z, x0.w, x1.x, x1.y, x1.z, x1.w};
#pragma unroll
      for (int e = 0; e < 8; ++e) {
        ushort hs = f2bf(vv[e]);
        ah[g][ks].u[e] = hs;
        al[g][ks].u[e] = f2bf(vv[e] - bf2f(hs));
      }
    }
  }

  float b1[16], b2[16];         // packed top-2 of m = z.e - e^2/2 (index in low 10 bits)
#pragma unroll
  for (int q = 0; q < 16; ++q) { b1[q] = -3.4e38f; b2[q] = -3.4e38f; }

  for (int s = 0; s < 4; ++s) {
    __syncthreads();            // drains vmcnt: buf[s&1] ready; prev compute done
    if (s < 3) {                // T3 2-phase: issue next-strip DMA before compute
      const int4* src = ef4 + (size_t)(cg * 4 + s + 1) * 1024 + ct;
      int4* dst = &ebuf[cg][(s + 1) & 1][ct];
#pragma unroll
      for (int k = 0; k < 4; ++k) gload16(src + k * 256, dst + k * 256);
    }

    const short8* bp = (const short8*)&ebuf[cg][s & 1][0];
    const int sbase = (cg * 4 + s) * 64;
#pragma unroll
    for (int t = 0; t < 4; ++t) {
      float cinit = e2s[sbase + t * 16 + col];
      f32x4 cc = {cinit, cinit, cinit, cinit};
      int invc = invLane - (sbase + t * 16);

      B8 bh0, bl0;
      bh0.s = bp[(t * 4 + 0) * 64 + lane];
      bl0.s = bp[(t * 4 + 1) * 64 + lane];
      f32x4 a0 = __builtin_amdgcn_mfma_f32_16x16x32_bf16(ah[0][0].v, bh0.v, cc, 0, 0, 0);
      f32x4 a1 = __builtin_amdgcn_mfma_f32_16x16x32_bf16(ah[1][0].v, bh0.v, cc, 0, 0, 0);
      f32x4 a2 = __builtin_amdgcn_mfma_f32_16x16x32_bf16(ah[2][0].v, bh0.v, cc, 0, 0, 0);
      f32x4 a3 = __builtin_amdgcn_mfma_f32_16x16x32_bf16(ah[3][0].v, bh0.v, cc, 0, 0, 0);
      a0 = __builtin_amdgcn_mfma_f32_16x16x32_bf16(al[0][0].v, bh0.v, a0, 0, 0, 0);
      a1 = __builtin_amdgcn_mfma_f32_16x16x32_bf16(al[1][0].v, bh0.v, a1, 0, 0, 0);
      a2 = __builtin_amdgcn_mfma_f32_16x16x32_bf16(al[2][0].v, bh0.v, a2, 0, 0, 0);
      a3 = __builtin_amdgcn_mfma_f32_16x16x32_bf16(al[3][0].v, bh0.v, a3, 0, 0, 0);
      a0 = __builtin_amdgcn_mfma_f32_16x16x32_bf16(ah[0][0].v, bl0.v, a0, 0, 0, 0);
      a1 = __builtin_amdgcn_mfma_f32_16x16x32_bf16(ah[1][0].v, bl0.v, a1, 0, 0, 0);
      a2 = __builtin_amdgcn_mfma_f32_16x16x32_bf16(ah[2][0].v, bl0.v, a2, 0, 0, 0);
      a3 = __builtin_amdgcn_mfma_f32_16x16x32_bf16(ah[3][0].v, bl0.v, a3, 0, 0, 0);

      B8 bh1, bl1;
      bh1.s = bp[(t * 4 + 2) * 64 + lane];
      bl1.s = bp[(t * 4 + 3) * 64 + lane];
      a0 = __builtin_amdgcn_mfma_f32_16x16x32_bf16(ah[0][1].v, bh1.v, a0, 0, 0, 0);
      a1 = __builtin_amdgcn_mfma_f32_16x16x32_bf16(ah[1][1].v, bh1.v, a1, 0, 0, 0);
      a2 = __builtin_amdgcn_mfma_f32_16x16x32_bf16(ah[2][1].v, bh1.v, a2, 0, 0, 0);
      a3 = __builtin_amdgcn_mfma_f32_16x16x32_bf16(ah[3][1].v, bh1.v, a3, 0, 0, 0);
      a0 = __builtin_amdgcn_mfma_f32_16x16x32_bf16(al[0][1].v, bh1.v, a0, 0, 0, 0);
      a1 = __builtin_amdgcn_mfma_f32_16x16x32_bf16(al[1][1].v, bh1.v, a1, 0, 0, 0);
      a2 = __builtin_amdgcn_mfma_f32_16x16x32_bf16(al[2][1].v, bh1.v, a2, 0, 0, 0);
      a3 = __builtin_amdgcn_mfma_f32_16x16x32_bf16(al[3][1].v, bh1.v, a3, 0, 0, 0);
      a0 = __builtin_amdgcn_mfma_f32_16x16x32_bf16(ah[0][1].v, bl1.v, a0, 0, 0, 0);
      a1 = __builtin_amdgcn_mfma_f32_16x16x32_bf16(ah[1][1].v, bl1.v, a1, 0, 0, 0);
      a2 = __builtin_amdgcn_mfma_f32_16x16x32_bf16(ah[2][1].v, bl1.v, a2, 0, 0, 0);
      a3 = __builtin_amdgcn_mfma_f32_16x16x32_bf16(ah[3][1].v, bl1.v, a3, 0, 0, 0);

      f32x4 av[4] = {a0, a1, a2, a3};
#pragma unroll
      for (int g = 0; g < 4; ++g)
#pragma unroll
        for (int r = 0; r < 4; ++r) {
          int q = g * 4 + r;
          unsigned mb = (__float_as_uint(av[g][r]) & 0xFFFFFC00u) | (unsigned)invc;
          float mp = __uint_as_float(mb);
          float nb2 = __builtin_amdgcn_fmed3f(mp, b1[q], b2[q]);
          b1[q] = fmaxf(b1[q], mp);
          b2[q] = nb2;
        }
    }
  }

  __syncthreads();                       // all strip compute done; reuse ebuf as merge buf
  float2* redm = (float2*)&ebuf[0][0][0];  // [cg*4+quad][256 rows]
#pragma unroll
  for (int q = 0; q < 16; ++q) {
    float m1 = b1[q], m2 = b2[q];
#pragma unroll
    for (int off = 1; off <= 2; off <<= 1) {
      float om1 = __shfl_xor(m1, off, 64);
      float om2 = __shfl_xor(m2, off, 64);
      float mx2 = fmaxf(m2, om2);
      m2 = __builtin_amdgcn_fmed3f(m1, om1, mx2);
      m1 = fmaxf(m1, om1);
    }
    if ((col & 3) == 0) {
      int quad = col >> 2;
      int row = rg * 64 + (q >> 2) * 16 + kq * 4 + (q & 3);
      redm[(cg * 4 + quad) * 256 + row] = make_float2(m1, m2);
    }
  }
  __syncthreads();

  if (tid < 256) {
    int row = tid;
    float M1 = -3.4e38f, M2 = -3.4e38f;
#pragma unroll
    for (int e = 0; e < 16; ++e) {
      float2 v = redm[e * 256 + row];
      float mx2 = fmaxf(M2, v.y);
      M2 = __builtin_amdgcn_fmed3f(M1, v.x, mx2);
      M1 = fmaxf(M1, v.x);
    }
    int grow = blockIdx.x * 256 + row;
    bool flg = (M1 - M2) < TAU_M;        // uncertified -> fp64 fixup
    int code = 1023 - (int)(__float_as_uint(M1) & 0x3FFu);
    WS_FLAGS(ws)[grow] = flg ? 1 : 0;
    win[row] = flg ? -1 : code;
    if (!flg) atomicAdd(&WS_COUNTS(ws)[code], 1);
  }
  __syncthreads();

  // gather + quantized_st + sse (4 threads/row, coalesced; skip flagged rows)
  float ssep = 0.f;
  {
    int row = tid >> 2, qtr = tid & 3;
    int wv = win[row];
    if (wv >= 0) {
      size_t grow = (size_t)blockIdx.x * 256 + row;
      const float4* epg = (const float4*)(emb + (size_t)wv * DIM) + qtr * 4;
      const float4* zp  = (const float4*)(z + grow * DIM) + qtr * 4;
      float4* op = (float4*)(outp + grow * DIM) + qtr * 4;
#pragma unroll
      for (int j = 0; j < 4; ++j) {
        float4 e = epg[j], zz = zp[j];
        float4 qv;
        qv.x = zz.x + (e.x - zz.x); qv.y = zz.y + (e.y - zz.y);
        qv.z = zz.z + (e.z - zz.z); qv.w = zz.w + (e.w - zz.w);
        op[j] = qv;
        float dx = zz.x - e.x, dy = zz.y - e.y, dz = zz.z - e.z, dw = zz.w - e.w;
        ssep += dx * dx + dy * dy + dz * dz + dw * dw;
      }
    }
  }
  for (int off = 32; off; off >>= 1) ssep += __shfl_down(ssep, off, 64);
  if (lane == 0) ssew[w] = ssep;
  __syncthreads();
  if (tid == 0) {
    float ts = 0.f;
#pragma unroll
    for (int i = 0; i < 16; ++i) ts += ssew[i];
    atomicAdd(WS_SSE(ws), ts);
  }
}

// --------------------------------------------------------------- fixup ----
// fp64 full re-score of flagged rows; writes their out rows, counts, sse.
__global__ __launch_bounds__(256) void vq_fixup(const float* __restrict__ z,
                                                const float* __restrict__ emb,
                                                void* ws,
                                                float* __restrict__ out) {
  const int CH = NROWS / 1024;   // 64 rows per block, grid = 1024
  int base = blockIdx.x * CH;
  int tid = threadIdx.x;

  __shared__ int list[CH];
  __shared__ int nlist;
  __shared__ __align__(16) float zrow[DIM];
  __shared__ double rd[256];
  __shared__ int    ri[256];

  if (tid == 0) nlist = 0;
  __syncthreads();
  if (tid < CH && WS_FLAGS(ws)[base + tid]) {
    int p = atomicAdd(&nlist, 1);
    list[p] = base + tid;
  }
  __syncthreads();
  int n = nlist;

  for (int q = 0; q < n; ++q) {
    int row = list[q];
    if (tid < 16) *(float4*)&zrow[tid * 4] = ((const float4*)(z + (size_t)row * DIM))[tid];
    __syncthreads();

    double bd = 1e300; int bi = 0x7fffffff;
    for (int c = tid; c < KCODE; c += 256) {
      const float4* e4 = (const float4*)(emb + (size_t)c * DIM);
      double dot = 0.0, e2 = 0.0;
#pragma unroll
      for (int t = 0; t < 16; ++t) {
        float4 v = e4[t];
        float4 zz = *(const float4*)&zrow[t * 4];
        dot = fma((double)zz.x, (double)v.x, dot);
        dot = fma((double)zz.y, (double)v.y, dot);
        dot = fma((double)zz.z, (double)v.z, dot);
        dot = fma((double)zz.w, (double)v.w, dot);
        e2  = fma((double)v.x, (double)v.x, e2);
        e2  = fma((double)v.y, (double)v.y, e2);
        e2  = fma((double)v.z, (double)v.z, e2);
        e2  = fma((double)v.w, (double)v.w, e2);
      }
      double dist = e2 - 2.0 * dot;
      if (dist < bd || (dist == bd && c < bi)) { bd = dist; bi = c; }
    }
    rd[tid] = bd; ri[tid] = bi;
    __syncthreads();
    for (int st = 128; st; st >>= 1) {
      if (tid < st) {
        double od = rd[tid + st]; int oi = ri[tid + st];
        if (od < rd[tid] || (od == rd[tid] && oi < ri[tid])) { rd[tid] = od; ri[tid] = oi; }
      }
      __syncthreads();
    }
    int wi = ri[0];
    if (tid < 16) {
      float4 e  = ((const float4*)(emb + (size_t)wi * DIM))[tid];
      float4 zz = *(const float4*)&zrow[tid * 4];
      float4 qv;
      qv.x = zz.x + (e.x - zz.x); qv.y = zz.y + (e.y - zz.y);
      qv.z = zz.z + (e.z - zz.z); qv.w = zz.w + (e.w - zz.w);
      ((float4*)(out + (size_t)row * DIM))[tid] = qv;
      float dx = zz.x - e.x, dy = zz.y - e.y, dz = zz.z - e.z, dw = zz.w - e.w;
      float part = dx * dx + dy * dy + dz * dz + dw * dw;
      part += __shfl_down(part, 8, 64);
      part += __shfl_down(part, 4, 64);
      part += __shfl_down(part, 2, 64);
      part += __shfl_down(part, 1, 64);
      if (tid == 0) {
        atomicAdd(WS_SSE(ws), part);
        atomicAdd(&WS_COUNTS(ws)[wi], 1);
      }
    }
    __syncthreads();
  }
}

// ------------------------------------------------------------ finalize ----
__global__ __launch_bounds__(256) void vq_finalize(void* ws, float* __restrict__ out) {
  int tid = threadIdx.x;
  __shared__ float w4[4];
  float part = 0.f;
  for (int c = tid; c < KCODE; c += 256) {
    float p = (float)WS_COUNTS(ws)[c] * (1.0f / (float)NROWS);
    part += p * logf(p + 1e-10f);
  }
  for (int off = 32; off; off >>= 1) part += __shfl_down(part, off, 64);
  if ((tid & 63) == 0) w4[tid >> 6] = part;
  __syncthreads();
  if (tid == 0) {
    float ent = (w4[0] + w4[1]) + (w4[2] + w4[3]);
    float perp = expf(-ent);
    perp = fminf(perp, (float)KCODE);
    if (!isfinite(perp)) perp = 0.f;
    out[(size_t)NROWS * DIM]     = 0.25f * (*WS_SSE(ws)) / (float)((size_t)NROWS * DIM);
    out[(size_t)NROWS * DIM + 1] = perp;
  }
}

extern "C" void kernel_launch(void* const* d_in, const int* in_sizes, int n_in,
                              void* d_out, int out_size, void* d_ws, size_t ws_size,
                              hipStream_t stream) {
  const float* z   = (const float*)d_in[0];
  const float* emb = (const float*)d_in[1];
  float* out = (float*)d_out;
  (void)in_sizes; (void)n_in; (void)out_size; (void)ws_size;

  vq_init    <<<16,   256,  0, stream>>>(emb, d_ws);
  vq_main    <<<NROWS / 256, 1024, 0, stream>>>(z, emb, d_ws, out);
  vq_fixup   <<<1024, 256,  0, stream>>>(z, emb, d_ws, out);
  vq_finalize<<<1,    256,  0, stream>>>(d_ws, out);
}

// Round 4
// 154.349 us; speedup vs baseline: 1.1936x; 1.1936x over previous
//
#include <hip/hip_runtime.h>
#include <math.h>

#define NROWS 65536      // B*T
#define DIM   64
#define KCODE 1024
#define TAU_M 8e-3f      // packed-margin threshold (split err ~1e-3 + packing err <=2.4e-3)

typedef __attribute__((ext_vector_type(8))) short short8;
typedef __bf16 bf16_t;
typedef bf16_t bf16x8 __attribute__((ext_vector_type(8)));
typedef __attribute__((ext_vector_type(4))) float f32x4;

union B8 { bf16x8 v; short8 s; ushort u[8]; };

// ws layout (bytes):
//   [0      .. 262143]  ushort emb_frag  (1024 codes x 64 dims x {hi,lo}) in MFMA B order
//   [262144 .. 266239]  float  e2h[1024]  = -(||e||^2 - 64) / 2   (shifted: argmin-invariant)
//   [266240 .. 270335]  int    counts[1024]
//   [270336 .. 270339]  float  sse
//   [270352 .. 335887]  uchar  flags[NROWS]
#define WS_EMBF(ws)   ((ushort*)(ws))
#define WS_E2H(ws)    ((float*)((char*)(ws) + 262144))
#define WS_COUNTS(ws) ((int*)((char*)(ws) + 266240))
#define WS_SSE(ws)    ((float*)((char*)(ws) + 270336))
#define WS_FLAGS(ws)  ((unsigned char*)(ws) + 270352)

__device__ __forceinline__ ushort f2bf(float x) {
  unsigned u = __float_as_uint(x);
  u += 0x7FFFu + ((u >> 16) & 1u);           // RNE
  return (ushort)(u >> 16);
}
__device__ __forceinline__ float bf2f(ushort h) {
  return __uint_as_float(((unsigned)h) << 16);
}

__device__ __forceinline__ void gload16(const int4* g, int4* l) {
  __builtin_amdgcn_global_load_lds((const __attribute__((address_space(1))) void*)g,
                                   (__attribute__((address_space(3))) void*)l, 16, 0, 0);
}

// ---------------------------------------------------------------- init ----
// grid 64 blocks x 256 threads; block = one 16-code tile (4KB fragment image).
// Thread t: code c = t&15, dims (t>>4)*4 .. +3. Also e2h, counts, sse.
__global__ __launch_bounds__(256) void vq_init(const float* __restrict__ emb, void* ws) {
  __shared__ __align__(16) ushort timg[2048];   // 4KB tile image
  __shared__ float e2p[256];

  const int g = blockIdx.x, t = threadIdx.x;    // g = global tile (16 codes)
  const int cl = t & 15;                        // local code (= MFMA col)
  const int d0 = (t >> 4) * 4;                  // dim range start
  const int gc = g * 16 + cl;

  const float4 v = *(const float4*)(emb + (size_t)gc * DIM + d0);
  float xs[4] = {v.x, v.y, v.z, v.w};
  float acc = 0.f;
#pragma unroll
  for (int u = 0; u < 4; ++u) {
    int d = d0 + u;
    float x = xs[u];
    ushort hs = f2bf(x);
    ushort ls = f2bf(x - bf2f(hs));
    int ks = d >> 5, kq = (d >> 3) & 3, e = d & 7;
    int lane = cl + kq * 16;
    int off = ks * 1024 + lane * 8 + e;         // ushort units within tile image
    timg[off] = hs;
    timg[off + 512] = ls;
    acc += x * x;
  }
  e2p[t] = acc;
  __syncthreads();
  if (t < 16) {
    float s = 0.f;
#pragma unroll
    for (int j = 0; j < 16; ++j) s += e2p[t + 16 * j];
    WS_E2H(ws)[g * 16 + t] = -0.5f * (s - 64.0f);   // shifted offset
    WS_COUNTS(ws)[g * 16 + t] = 0;
  }
  if (g == 0 && t == 0) *WS_SSE(ws) = 0.f;
  __syncthreads();
  ((int4*)WS_EMBF(ws))[g * 256 + t] = ((const int4*)timg)[t];
}

// ---------------------------------------------------------------- main ----
// 1024 threads = 16 waves = 4 row-groups x 4 code-groups; block = 256 rows;
// grid = 256 (1 block/CU, 4 waves/SIMD). Code-group owns 4 strips (256 codes),
// double-buffered via global_load_lds.
__global__ __launch_bounds__(1024, 4) void vq_main(const float* __restrict__ z,
                                                   const float* __restrict__ emb,
                                                   void* ws,
                                                   float* __restrict__ outp) {
  __shared__ __align__(16) int4 ebuf[4][2][1024];   // [cgroup][dbuf][16KB strip]
  __shared__ float e2s[KCODE];
  __shared__ int   win[256];
  __shared__ float ssew[16];

  const int tid  = threadIdx.x;
  const int lane = tid & 63, w = tid >> 6;
  const int rg = w & 3, cg = w >> 2;
  const int col = lane & 15, kq = lane >> 4;
  const int ct = tid & 255;                        // index within code-group
  const int rowbase = blockIdx.x * 256 + rg * 64;
  const int invLane = 1023 - col;

  const int4* ef4 = (const int4*)WS_EMBF(ws);

  // prologue stage: strip 0 of this cgroup -> ebuf[cg][0] (async DMA)
  {
    const int4* src = ef4 + (size_t)(cg * 4) * 1024 + ct;
    int4* dst = &ebuf[cg][0][ct];
#pragma unroll
    for (int k = 0; k < 4; ++k) gload16(src + k * 256, dst + k * 256);
  }
  // stage e2h -> LDS (4KB)
  if (tid < 256) ((float4*)e2s)[tid] = ((const float4*)WS_E2H(ws))[tid];

  // A fragments: 4 row-groups-of-16 x 2 ksteps, hi+lo, in registers all kernel
  B8 ah[4][2], al[4][2];
#pragma unroll
  for (int g = 0; g < 4; ++g) {
    int row = rowbase + g * 16 + col;
    const float* zr = z + (size_t)row * DIM;
#pragma unroll
    for (int ks = 0; ks < 2; ++ks) {
      const float4* p = (const float4*)(zr + ks * 32 + kq * 8);
      float4 x0 = p[0], x1 = p[1];
      float vv[8] = {x0.x, x0.y, x0.z, x0.w, x1.x, x1.y, x1.z, x1.w};
#pragma unroll
      for (int e = 0; e < 8; ++e) {
        ushort hs = f2bf(vv[e]);
        ah[g][ks].u[e] = hs;
        al[g][ks].u[e] = f2bf(vv[e] - bf2f(hs));
      }
    }
  }

  float b1[16], b2[16];         // packed top-2 of m = z.e - (e^2-64)/2 (index in low 10 bits)
#pragma unroll
  for (int q = 0; q < 16; ++q) { b1[q] = -3.4e38f; b2[q] = -3.4e38f; }

  for (int s = 0; s < 4; ++s) {
    __syncthreads();            // drains vmcnt: buf[s&1] ready; prev compute done
    if (s < 3) {                // T3 2-phase: issue next-strip DMA before compute
      const int4* src = ef4 + (size_t)(cg * 4 + s + 1) * 1024 + ct;
      int4* dst = &ebuf[cg][(s + 1) & 1][ct];
#pragma unroll
      for (int k = 0; k < 4; ++k) gload16(src + k * 256, dst + k * 256);
    }

    const short8* bp = (const short8*)&ebuf[cg][s & 1][0];
    const int sbase = (cg * 4 + s) * 64;
#pragma unroll
    for (int t = 0; t < 4; ++t) {
      float cinit = e2s[sbase + t * 16 + col];
      f32x4 cc = {cinit, cinit, cinit, cinit};
      int invc = invLane - (sbase + t * 16);

      B8 bh0, bl0;
      bh0.s = bp[(t * 4 + 0) * 64 + lane];
      bl0.s = bp[(t * 4 + 1) * 64 + lane];
      f32x4 a0 = __builtin_amdgcn_mfma_f32_16x16x32_bf16(ah[0][0].v, bh0.v, cc, 0, 0, 0);
      f32x4 a1 = __builtin_amdgcn_mfma_f32_16x16x32_bf16(ah[1][0].v, bh0.v, cc, 0, 0, 0);
      f32x4 a2 = __builtin_amdgcn_mfma_f32_16x16x32_bf16(ah[2][0].v, bh0.v, cc, 0, 0, 0);
      f32x4 a3 = __builtin_amdgcn_mfma_f32_16x16x32_bf16(ah[3][0].v, bh0.v, cc, 0, 0, 0);
      a0 = __builtin_amdgcn_mfma_f32_16x16x32_bf16(al[0][0].v, bh0.v, a0, 0, 0, 0);
      a1 = __builtin_amdgcn_mfma_f32_16x16x32_bf16(al[1][0].v, bh0.v, a1, 0, 0, 0);
      a2 = __builtin_amdgcn_mfma_f32_16x16x32_bf16(al[2][0].v, bh0.v, a2, 0, 0, 0);
      a3 = __builtin_amdgcn_mfma_f32_16x16x32_bf16(al[3][0].v, bh0.v, a3, 0, 0, 0);
      a0 = __builtin_amdgcn_mfma_f32_16x16x32_bf16(ah[0][0].v, bl0.v, a0, 0, 0, 0);
      a1 = __builtin_amdgcn_mfma_f32_16x16x32_bf16(ah[1][0].v, bl0.v, a1, 0, 0, 0);
      a2 = __builtin_amdgcn_mfma_f32_16x16x32_bf16(ah[2][0].v, bl0.v, a2, 0, 0, 0);
      a3 = __builtin_amdgcn_mfma_f32_16x16x32_bf16(ah[3][0].v, bl0.v, a3, 0, 0, 0);

      B8 bh1, bl1;
      bh1.s = bp[(t * 4 + 2) * 64 + lane];
      bl1.s = bp[(t * 4 + 3) * 64 + lane];
      a0 = __builtin_amdgcn_mfma_f32_16x16x32_bf16(ah[0][1].v, bh1.v, a0, 0, 0, 0);
      a1 = __builtin_amdgcn_mfma_f32_16x16x32_bf16(ah[1][1].v, bh1.v, a1, 0, 0, 0);
      a2 = __builtin_amdgcn_mfma_f32_16x16x32_bf16(ah[2][1].v, bh1.v, a2, 0, 0, 0);
      a3 = __builtin_amdgcn_mfma_f32_16x16x32_bf16(ah[3][1].v, bh1.v, a3, 0, 0, 0);
      a0 = __builtin_amdgcn_mfma_f32_16x16x32_bf16(al[0][1].v, bh1.v, a0, 0, 0, 0);
      a1 = __builtin_amdgcn_mfma_f32_16x16x32_bf16(al[1][1].v, bh1.v, a1, 0, 0, 0);
      a2 = __builtin_amdgcn_mfma_f32_16x16x32_bf16(al[2][1].v, bh1.v, a2, 0, 0, 0);
      a3 = __builtin_amdgcn_mfma_f32_16x16x32_bf16(al[3][1].v, bh1.v, a3, 0, 0, 0);
      a0 = __builtin_amdgcn_mfma_f32_16x16x32_bf16(ah[0][1].v, bl1.v, a0, 0, 0, 0);
      a1 = __builtin_amdgcn_mfma_f32_16x16x32_bf16(ah[1][1].v, bl1.v, a1, 0, 0, 0);
      a2 = __builtin_amdgcn_mfma_f32_16x16x32_bf16(ah[2][1].v, bl1.v, a2, 0, 0, 0);
      a3 = __builtin_amdgcn_mfma_f32_16x16x32_bf16(ah[3][1].v, bl1.v, a3, 0, 0, 0);

      f32x4 av[4] = {a0, a1, a2, a3};
#pragma unroll
      for (int g = 0; g < 4; ++g)
#pragma unroll
        for (int r = 0; r < 4; ++r) {
          int q = g * 4 + r;
          unsigned mb = (__float_as_uint(av[g][r]) & 0xFFFFFC00u) | (unsigned)invc;
          float mp = __uint_as_float(mb);
          float nb2 = __builtin_amdgcn_fmed3f(mp, b1[q], b2[q]);
          b1[q] = fmaxf(b1[q], mp);
          b2[q] = nb2;
        }
    }
  }

  __syncthreads();                       // all strip compute done; reuse ebuf as merge buf
  float2* redm = (float2*)&ebuf[0][0][0];  // [cg*4+quad][256 rows]
#pragma unroll
  for (int q = 0; q < 16; ++q) {
    float m1 = b1[q], m2 = b2[q];
#pragma unroll
    for (int off = 1; off <= 2; off <<= 1) {
      float om1 = __shfl_xor(m1, off, 64);
      float om2 = __shfl_xor(m2, off, 64);
      float mx2 = fmaxf(m2, om2);
      m2 = __builtin_amdgcn_fmed3f(m1, om1, mx2);
      m1 = fmaxf(m1, om1);
    }
    if ((col & 3) == 0) {
      int quad = col >> 2;
      int row = rg * 64 + (q >> 2) * 16 + kq * 4 + (q & 3);
      redm[(cg * 4 + quad) * 256 + row] = make_float2(m1, m2);
    }
  }
  __syncthreads();

  if (tid < 256) {
    int row = tid;
    float M1 = -3.4e38f, M2 = -3.4e38f;
#pragma unroll
    for (int e = 0; e < 16; ++e) {
      float2 v = redm[e * 256 + row];
      float mx2 = fmaxf(M2, v.y);
      M2 = __builtin_amdgcn_fmed3f(M1, v.x, mx2);
      M1 = fmaxf(M1, v.x);
    }
    int grow = blockIdx.x * 256 + row;
    bool flg = (M1 - M2) < TAU_M;        // uncertified -> fp64 fixup
    int code = 1023 - (int)(__float_as_uint(M1) & 0x3FFu);
    WS_FLAGS(ws)[grow] = flg ? 1 : 0;
    win[row] = flg ? -1 : code;
    if (!flg) atomicAdd(&WS_COUNTS(ws)[code], 1);
  }
  __syncthreads();

  // gather + quantized_st + sse (4 threads/row, coalesced; skip flagged rows)
  float ssep = 0.f;
  {
    int row = tid >> 2, qtr = tid & 3;
    int wv = win[row];
    if (wv >= 0) {
      size_t grow = (size_t)blockIdx.x * 256 + row;
      const float4* epg = (const float4*)(emb + (size_t)wv * DIM) + qtr * 4;
      const float4* zp  = (const float4*)(z + grow * DIM) + qtr * 4;
      float4* op = (float4*)(outp + grow * DIM) + qtr * 4;
#pragma unroll
      for (int j = 0; j < 4; ++j) {
        float4 e = epg[j], zz = zp[j];
        float4 qv;
        qv.x = zz.x + (e.x - zz.x); qv.y = zz.y + (e.y - zz.y);
        qv.z = zz.z + (e.z - zz.z); qv.w = zz.w + (e.w - zz.w);
        op[j] = qv;
        float dx = zz.x - e.x, dy = zz.y - e.y, dz = zz.z - e.z, dw = zz.w - e.w;
        ssep += dx * dx + dy * dy + dz * dz + dw * dw;
      }
    }
  }
  for (int off = 32; off; off >>= 1) ssep += __shfl_down(ssep, off, 64);
  if (lane == 0) ssew[w] = ssep;
  __syncthreads();
  if (tid == 0) {
    float ts = 0.f;
#pragma unroll
    for (int i = 0; i < 16; ++i) ts += ssew[i];
    atomicAdd(WS_SSE(ws), ts);
  }
}

// --------------------------------------------------------------- fixup ----
// fp64 full re-score of flagged rows; writes their out rows, counts, sse.
__global__ __launch_bounds__(256) void vq_fixup(const float* __restrict__ z,
                                                const float* __restrict__ emb,
                                                void* ws,
                                                float* __restrict__ out) {
  const int CH = NROWS / 1024;   // 64 rows per block, grid = 1024
  int base = blockIdx.x * CH;
  int tid = threadIdx.x;

  __shared__ int list[CH];
  __shared__ int nlist;
  __shared__ __align__(16) float zrow[DIM];
  __shared__ double rd[256];
  __shared__ int    ri[256];

  if (tid == 0) nlist = 0;
  __syncthreads();
  if (tid < CH && WS_FLAGS(ws)[base + tid]) {
    int p = atomicAdd(&nlist, 1);
    list[p] = base + tid;
  }
  __syncthreads();
  int n = nlist;

  for (int q = 0; q < n; ++q) {
    int row = list[q];
    if (tid < 16) *(float4*)&zrow[tid * 4] = ((const float4*)(z + (size_t)row * DIM))[tid];
    __syncthreads();

    double bd = 1e300; int bi = 0x7fffffff;
    for (int c = tid; c < KCODE; c += 256) {
      const float4* e4 = (const float4*)(emb + (size_t)c * DIM);
      double dot = 0.0, e2 = 0.0;
#pragma unroll
      for (int t = 0; t < 16; ++t) {
        float4 v = e4[t];
        float4 zz = *(const float4*)&zrow[t * 4];
        dot = fma((double)zz.x, (double)v.x, dot);
        dot = fma((double)zz.y, (double)v.y, dot);
        dot = fma((double)zz.z, (double)v.z, dot);
        dot = fma((double)zz.w, (double)v.w, dot);
        e2  = fma((double)v.x, (double)v.x, e2);
        e2  = fma((double)v.y, (double)v.y, e2);
        e2  = fma((double)v.z, (double)v.z, e2);
        e2  = fma((double)v.w, (double)v.w, e2);
      }
      double dist = e2 - 2.0 * dot;
      if (dist < bd || (dist == bd && c < bi)) { bd = dist; bi = c; }
    }
    rd[tid] = bd; ri[tid] = bi;
    __syncthreads();
    for (int st = 128; st; st >>= 1) {
      if (tid < st) {
        double od = rd[tid + st]; int oi = ri[tid + st];
        if (od < rd[tid] || (od == rd[tid] && oi < ri[tid])) { rd[tid] = od; ri[tid] = oi; }
      }
      __syncthreads();
    }
    int wi = ri[0];
    if (tid < 16) {
      float4 e  = ((const float4*)(emb + (size_t)wi * DIM))[tid];
      float4 zz = *(const float4*)&zrow[tid * 4];
      float4 qv;
      qv.x = zz.x + (e.x - zz.x); qv.y = zz.y + (e.y - zz.y);
      qv.z = zz.z + (e.z - zz.z); qv.w = zz.w + (e.w - zz.w);
      ((float4*)(out + (size_t)row * DIM))[tid] = qv;
      float dx = zz.x - e.x, dy = zz.y - e.y, dz = zz.z - e.z, dw = zz.w - e.w;
      float part = dx * dx + dy * dy + dz * dz + dw * dw;
      part += __shfl_down(part, 8, 64);
      part += __shfl_down(part, 4, 64);
      part += __shfl_down(part, 2, 64);
      part += __shfl_down(part, 1, 64);
      if (tid == 0) {
        atomicAdd(WS_SSE(ws), part);
        atomicAdd(&WS_COUNTS(ws)[wi], 1);
      }
    }
    __syncthreads();
  }
}

// ------------------------------------------------------------ finalize ----
__global__ __launch_bounds__(256) void vq_finalize(void* ws, float* __restrict__ out) {
  int tid = threadIdx.x;
  __shared__ float w4[4];
  float part = 0.f;
  for (int c = tid; c < KCODE; c += 256) {
    float p = (float)WS_COUNTS(ws)[c] * (1.0f / (float)NROWS);
    part += p * logf(p + 1e-10f);
  }
  for (int off = 32; off; off >>= 1) part += __shfl_down(part, off, 64);
  if ((tid & 63) == 0) w4[tid >> 6] = part;
  __syncthreads();
  if (tid == 0) {
    float ent = (w4[0] + w4[1]) + (w4[2] + w4[3]);
    float perp = expf(-ent);
    perp = fminf(perp, (float)KCODE);
    if (!isfinite(perp)) perp = 0.f;
    out[(size_t)NROWS * DIM]     = 0.25f * (*WS_SSE(ws)) / (float)((size_t)NROWS * DIM);
    out[(size_t)NROWS * DIM + 1] = perp;
  }
}

extern "C" void kernel_launch(void* const* d_in, const int* in_sizes, int n_in,
                              void* d_out, int out_size, void* d_ws, size_t ws_size,
                              hipStream_t stream) {
  const float* z   = (const float*)d_in[0];
  const float* emb = (const float*)d_in[1];
  float* out = (float*)d_out;
  (void)in_sizes; (void)n_in; (void)out_size; (void)ws_size;

  vq_init    <<<64,   256,  0, stream>>>(emb, d_ws);
  vq_main    <<<NROWS / 256, 1024, 0, stream>>>(z, emb, d_ws, out);
  vq_fixup   <<<1024, 256,  0, stream>>>(z, emb, d_ws, out);
  vq_finalize<<<1,    256,  0, stream>>>(d_ws, out);
}